// Round 2
// baseline (188.498 us; speedup 1.0000x reference)
//
#include <hip/hip_runtime.h>
#include <math.h>

namespace {
constexpr int kB = 4;
constexpr int kS = 4096;
constexpr int kD = 1024;
constexpr int kM = 128;
constexpr int kC = 64;           // chunk length
constexpr int kNC = kS / kC;     // 64 chunks per batch
constexpr int kNCG = kB * kNC;   // 256 global chunks
constexpr int kRS = kB * kS;     // 16384 rows
constexpr float kLR = 0.01f;
constexpr float kLog2d = -0.0144995696f;   // log2(0.99)
}

typedef __bf16 bf16x8 __attribute__((ext_vector_type(8)));
typedef float  f32x4  __attribute__((ext_vector_type(4)));
typedef unsigned short u16;
typedef unsigned int   u32;

__device__ __forceinline__ u16 f2bf(float f) {
  u32 x = __float_as_uint(f);
  u32 r = (x + 0x7fffu + ((x >> 16) & 1u)) >> 16;   // RNE
  return (u16)r;
}

__device__ __forceinline__ float bf2f(u16 h) {
  return __uint_as_float(((u32)h) << 16);
}

__device__ __forceinline__ void gl_lds16(const void* g, void* l) {
  __builtin_amdgcn_global_load_lds(
      (const __attribute__((address_space(1))) void*)g,
      (__attribute__((address_space(3))) void*)l, 16, 0, 0);
}

__device__ __forceinline__ f32x4 mf(bf16x8 a, bf16x8 b, f32x4 c) {
  return __builtin_amdgcn_mfma_f32_16x16x32_bf16(a, b, c, 0, 0, 0);
}

__device__ __forceinline__ ushort4 pack4(float4 a) {
  ushort4 o;
  o.x = f2bf(a.x); o.y = f2bf(a.y); o.z = f2bf(a.z); o.w = f2bf(a.w);
  return o;
}

// Fragment-panel layouts: 1 KiB panel = 16 rows x 32 cols bf16; element (r,c)
// at byte ((c>>3)&3)*256 + (r&15)*16 + (c&7)*2 within panel. A wave
// ds_read_b128 of one fragment (lane -> qd*256 + fr*16) is a contiguous 1 KiB.
__device__ __forceinline__ int fo64x128(int r, int c) {   // 64 rows x 128 cols
  return ((r >> 4) * 4 + (c >> 5)) * 1024 + ((c >> 3) & 3) * 256 + (r & 15) * 16 + (c & 7) * 2;
}
__device__ __forceinline__ int fo128x64(int r, int c) {   // 128 rows x 64 cols
  return ((r >> 4) * 2 + (c >> 5)) * 1024 + ((c >> 3) & 3) * 256 + (r & 15) * 16 + (c & 7) * 2;
}
__device__ __forceinline__ int fo64x64(int r, int c) {    // 64 rows x 64 cols
  return ((r >> 4) * 2 + (c >> 5)) * 1024 + ((c >> 3) & 3) * 256 + (r & 15) * 16 + (c & 7) * 2;
}

// ---------------------------------------------------------------------------
// cast Wk|Wv|Wq (concat -> Wkvq[384][1024]) and Wo -> Woh[1024][128], bf16
// ---------------------------------------------------------------------------
__global__ __launch_bounds__(256)
void cast_w_kernel(const float* __restrict__ Wk, const float* __restrict__ Wv,
                   const float* __restrict__ Wq, const float* __restrict__ Wo,
                   u16* __restrict__ Wkvq, u16* __restrict__ Woh)
{
  int i = (blockIdx.x * 256 + threadIdx.x) * 4;   // < 524288
  const float* src;
  u16* dst;
  if (i < 393216) {
    src = (i < 131072) ? Wk + i : (i < 262144) ? Wv + (i - 131072) : Wq + (i - 262144);
    dst = Wkvq + i;
  } else {
    src = Wo + (i - 393216);
    dst = Woh + (i - 393216);
  }
  float4 v = *(const float4*)src;
  *(ushort4*)dst = pack4(v);
}

// ---------------------------------------------------------------------------
// proj_gemm: C[16384 x 384] = x @ Wkvq^T (+bias in epilogue), tiled GEMM.
// Tile 64 rows (one chunk) x 128 cols (one slab: 0=K,1=V,2=Q).
// Grid (256 chunks, 3 slabs) = 768 blocks (~3/CU). 256 threads (4 waves,
// 2x2 wave grid: 32t x 64n each). BK=64, double-buffered; 48 KiB LDS.
// Epilogue (values in regs, fp32): writes chunk-fragment-layout outputs:
//   slab 0: Kg [64t x 128j] and KwTg [128j x 64t] (pre-scaled lr*d^{63-t})
//   slab 1: VTg [128i x 64t]           slab 2: Qg [64t x 128j]
// ---------------------------------------------------------------------------
__global__ __launch_bounds__(256, 3)
void proj_gemm(const float* __restrict__ x, const u16* __restrict__ Wkvq,
               const float* __restrict__ bk, const float* __restrict__ bv,
               const float* __restrict__ bq,
               u16* __restrict__ Qg, u16* __restrict__ Kg,
               u16* __restrict__ VTg, u16* __restrict__ KwTg)
{
  __shared__ __align__(16) u16 L[24576];   // 48 KiB
  const int cg = blockIdx.x, s = blockIdx.y;
  const int R0 = cg * 64;
  const int tid = threadIdx.x, w = tid >> 6, lane = tid & 63;
  const int fr = lane & 15, qd = lane >> 4;
  const int wr = w >> 1, wc = w & 1;

  constexpr int A0 = 0, A1o = 8192, B0 = 16384, B1o = 32768;   // byte offsets

  // A staging: thread -> row xr, 4 float4 groups at cols s4*4 + 16q
  const int xr = tid >> 2, s4 = tid & 3;
  const float* xp = x + (size_t)(R0 + xr) * kD + s4 * 4;
  int aoffq[4];
#pragma unroll
  for (int q = 0; q < 4; ++q)
    aoffq[q] = ((xr >> 4) * 2 + (q >> 1)) * 1024 + (((s4 >> 1) + 2 * q) & 3) * 256
             + (xr & 15) * 16 + (s4 & 1) * 8;

  // B staging: wave handles panels pn = 4w+g (16 total: ng=pn>>1, kh=pn&1)
  const u16* wbase = Wkvq + (size_t)(128 * s) * kD + qd * 8;

  f32x4 acc[2][4] = {};
  float4 xv[4];

  // prologue: stage step 0, prefetch x regs for step 1
  {
#pragma unroll
    for (int g = 0; g < 4; ++g) {
      const int pn = 4 * w + g, ng = pn >> 1, kh = pn & 1;
      gl_lds16(wbase + (size_t)(ng * 16 + fr) * kD + kh * 32, &L[(B0 + pn * 1024) >> 1]);
    }
    float4 x0[4];
#pragma unroll
    for (int q = 0; q < 4; ++q) x0[q] = *(const float4*)(xp + q * 16);
#pragma unroll
    for (int q = 0; q < 4; ++q) *(ushort4*)&L[(A0 + aoffq[q]) >> 1] = pack4(x0[q]);
#pragma unroll
    for (int q = 0; q < 4; ++q) xv[q] = *(const float4*)(xp + 64 + q * 16);
  }
  __syncthreads();

#pragma unroll 2
  for (int i = 0; i < 16; ++i) {
    const int Ac = (i & 1) ? A1o : A0, Bc = (i & 1) ? B1o : B0;
    const int An = (i & 1) ? A0 : A1o, Bn = (i & 1) ? B0 : B1o;
    if (i < 15) {
      const int k1 = (i + 1) * 64;
#pragma unroll
      for (int g = 0; g < 4; ++g) {
        const int pn = 4 * w + g, ng = pn >> 1, kh = pn & 1;
        gl_lds16(wbase + (size_t)(ng * 16 + fr) * kD + k1 + kh * 32, &L[(Bn + pn * 1024) >> 1]);
      }
#pragma unroll
      for (int q = 0; q < 4; ++q) *(ushort4*)&L[(An + aoffq[q]) >> 1] = pack4(xv[q]);
      if (i < 14) {
#pragma unroll
        for (int q = 0; q < 4; ++q) xv[q] = *(const float4*)(xp + (i + 2) * 64 + q * 16);
      }
    }
    bf16x8 af[2][2], bfr[2][4];
#pragma unroll
    for (int kh = 0; kh < 2; ++kh) {
#pragma unroll
      for (int mi = 0; mi < 2; ++mi)
        af[kh][mi] = *(const bf16x8*)&L[(Ac + ((wr * 2 + mi) * 2 + kh) * 1024 + qd * 256 + fr * 16) >> 1];
#pragma unroll
      for (int ng = 0; ng < 4; ++ng)
        bfr[kh][ng] = *(const bf16x8*)&L[(Bc + ((wc * 4 + ng) * 2 + kh) * 1024 + qd * 256 + fr * 16) >> 1];
    }
#pragma unroll
    for (int kh = 0; kh < 2; ++kh)
#pragma unroll
      for (int mi = 0; mi < 2; ++mi)
#pragma unroll
        for (int ng = 0; ng < 4; ++ng)
          acc[mi][ng] = mf(af[kh][mi], bfr[kh][ng], acc[mi][ng]);
    __syncthreads();
  }

  // epilogue: bias + per-slab stores (coords: t = wr*32+mi*16+qd*4+r,
  // n = wc*64+ng*16+fr)
  const float* bp = (s == 0) ? bk : (s == 1) ? bv : bq;
  float bias[4];
#pragma unroll
  for (int ng = 0; ng < 4; ++ng) bias[ng] = bp[wc * 64 + ng * 16 + fr];
  const size_t cb = (size_t)cg * 8192;

  if (s == 0) {
    float dp[2][4];
#pragma unroll
    for (int mi = 0; mi < 2; ++mi)
#pragma unroll
      for (int r = 0; r < 4; ++r)
        dp[mi][r] = kLR * exp2f((float)(63 - (wr * 32 + mi * 16 + qd * 4 + r)) * kLog2d);
#pragma unroll
    for (int mi = 0; mi < 2; ++mi)
#pragma unroll
      for (int ng = 0; ng < 4; ++ng)
#pragma unroll
        for (int r = 0; r < 4; ++r) {
          const int t = wr * 32 + mi * 16 + qd * 4 + r, n = wc * 64 + ng * 16 + fr;
          const float v = acc[mi][ng][r] + bias[ng];
          Kg[cb + (fo64x128(t, n) >> 1)] = f2bf(v);
          KwTg[cb + (fo128x64(n, t) >> 1)] = f2bf(v * dp[mi][r]);
        }
  } else if (s == 1) {
#pragma unroll
    for (int mi = 0; mi < 2; ++mi)
#pragma unroll
      for (int ng = 0; ng < 4; ++ng)
#pragma unroll
        for (int r = 0; r < 4; ++r) {
          const int t = wr * 32 + mi * 16 + qd * 4 + r, n = wc * 64 + ng * 16 + fr;
          VTg[cb + (fo128x64(n, t) >> 1)] = f2bf(acc[mi][ng][r] + bias[ng]);
        }
  } else {
#pragma unroll
    for (int mi = 0; mi < 2; ++mi)
#pragma unroll
      for (int ng = 0; ng < 4; ++ng)
#pragma unroll
        for (int r = 0; r < 4; ++r) {
          const int t = wr * 32 + mi * 16 + qd * 4 + r, n = wc * 64 + ng * 16 + fr;
          Qg[cb + (fo64x128(t, n) >> 1)] = f2bf(acc[mi][ng][r] + bias[ng]);
        }
  }
}

// ---------------------------------------------------------------------------
// intra_kernel: per chunk: P = Q K^T, At = mask/decay(P), O1 = At V^T,
// U = V^T KwT. 256 blocks, 256 threads. All operands staged identity via
// global_load_lds from fragment-layout global arrays. 64 KiB LDS:
// Q@0 K@16K VT@32K KwT@48K ; At (8K) overwrites Q after P.
// ---------------------------------------------------------------------------
__global__ __launch_bounds__(256, 2)
void intra_kernel(const u16* __restrict__ Qg, const u16* __restrict__ Kg,
                  const u16* __restrict__ VTg, const u16* __restrict__ KwTg,
                  u16* __restrict__ O1g, float* __restrict__ SU)
{
  __shared__ __align__(16) u16 L[32768];
  const int cg = blockIdx.x;
  const int tid = threadIdx.x, w = tid >> 6, lane = tid & 63;
  const int fr = lane & 15, qd = lane >> 4;
  const size_t cb = (size_t)cg * 8192;

#pragma unroll
  for (int g = 0; g < 4; ++g) {
    const int pn = 4 * w + g;
    gl_lds16(Qg + cb + pn * 512 + lane * 8, &L[(0 + pn * 1024) >> 1]);
    gl_lds16(Kg + cb + pn * 512 + lane * 8, &L[(16384 + pn * 1024) >> 1]);
    gl_lds16(VTg + cb + pn * 512 + lane * 8, &L[(32768 + pn * 1024) >> 1]);
    gl_lds16(KwTg + cb + pn * 512 + lane * 8, &L[(49152 + pn * 1024) >> 1]);
  }
  __syncthreads();

  // P: wave w covers t-rows 16w x all 64 u
  f32x4 p[4] = {};
#pragma unroll
  for (int kc = 0; kc < 4; ++kc) {
    bf16x8 aq = *(const bf16x8*)&L[(0 + (w * 4 + kc) * 1024 + qd * 256 + fr * 16) >> 1];
#pragma unroll
    for (int ug = 0; ug < 4; ++ug) {
      bf16x8 bkf = *(const bf16x8*)&L[(16384 + (ug * 4 + kc) * 1024 + qd * 256 + fr * 16) >> 1];
      p[ug] = mf(aq, bkf, p[ug]);
    }
  }
  __syncthreads();   // Q,K reads done; reuse Q region for At

  // At = mask/decay(P), fragment layout [64 x 64] at LDS 0
#pragma unroll
  for (int ug = 0; ug < 4; ++ug)
#pragma unroll
    for (int r = 0; r < 4; ++r) {
      const int t = w * 16 + qd * 4 + r, u = ug * 16 + fr;
      float av = 0.f;
      if (u < t) av = kLR * exp2f((float)(t - 1 - u) * kLog2d) * p[ug][r];
      L[(0 + fo64x64(t, u)) >> 1] = f2bf(av);
    }
  __syncthreads();

  // O1: wave w -> 16 t-rows x 128 i ; U: wave w -> 32 i-rows x 128 j
  f32x4 o1[8] = {}, uu[2][8] = {};
#pragma unroll
  for (int h = 0; h < 2; ++h) {
    bf16x8 aA = *(const bf16x8*)&L[(0 + (w * 2 + h) * 1024 + qd * 256 + fr * 16) >> 1];
    bf16x8 aV[2];
#pragma unroll
    for (int mi = 0; mi < 2; ++mi)
      aV[mi] = *(const bf16x8*)&L[(32768 + ((2 * w + mi) * 2 + h) * 1024 + qd * 256 + fr * 16) >> 1];
#pragma unroll
    for (int ig = 0; ig < 8; ++ig) {
      bf16x8 bV = *(const bf16x8*)&L[(32768 + (ig * 2 + h) * 1024 + qd * 256 + fr * 16) >> 1];
      o1[ig] = mf(aA, bV, o1[ig]);
    }
#pragma unroll
    for (int jg = 0; jg < 8; ++jg) {
      bf16x8 bK = *(const bf16x8*)&L[(49152 + (jg * 2 + h) * 1024 + qd * 256 + fr * 16) >> 1];
#pragma unroll
      for (int mi = 0; mi < 2; ++mi)
        uu[mi][jg] = mf(aV[mi], bK, uu[mi][jg]);
    }
  }

  // stores
#pragma unroll
  for (int ig = 0; ig < 8; ++ig)
#pragma unroll
    for (int r = 0; r < 4; ++r) {
      const int t = w * 16 + qd * 4 + r, i2 = ig * 16 + fr;
      O1g[cb + (fo64x128(t, i2) >> 1)] = f2bf(o1[ig][r]);
    }
  float* SUc = SU + (size_t)cg * 16384;
#pragma unroll
  for (int mi = 0; mi < 2; ++mi)
#pragma unroll
    for (int jg = 0; jg < 8; ++jg)
#pragma unroll
      for (int r = 0; r < 4; ++r) {
        const int i2 = w * 32 + mi * 16 + qd * 4 + r, j = jg * 16 + fr;
        SUc[i2 * kM + j] = uu[mi][jg][r];
      }
}

// ---------------------------------------------------------------------------
// inter-chunk scan: Sb16[c] = bf16(state before chunk c); carry -> state_out
// ---------------------------------------------------------------------------
__global__ __launch_bounds__(256)
void scan_kernel(const float* __restrict__ SU, u16* __restrict__ Sb16,
                 float* __restrict__ state_out)
{
  const int e = blockIdx.x * 256 + threadIdx.x;   // < kB * 16384
  const int b = e >> 14, ij = e & 16383;
  const float* base = SU + (size_t)b * kNC * 16384 + ij;
  u16* sb = Sb16 + (size_t)b * kNC * 16384 + ij;
  const float dC = exp2f((float)kC * kLog2d);
  float prev = 0.f;
#pragma unroll 8
  for (int c2 = 0; c2 < kNC; ++c2) {
    const float u = base[(size_t)c2 * 16384];
    sb[(size_t)c2 * 16384] = f2bf(prev);
    prev = fmaf(dC, prev, u);
  }
  state_out[e] = prev;
}

// ---------------------------------------------------------------------------
// combine_kernel: per chunk: O2 = Q S^T; Out = bf16(O1 + d^t O2) -> global
// fragment layout. 256 blocks, 256 threads, single barrier.
// LDS 64 KiB: Q@0 (16K), S@16K (32K), O1@48K (16K).
// ---------------------------------------------------------------------------
__global__ __launch_bounds__(256, 2)
void combine_kernel(const u16* __restrict__ Qg, const u16* __restrict__ Sb16,
                    const u16* __restrict__ O1g, u16* __restrict__ Outg)
{
  __shared__ __align__(16) u16 L[32768];
  const int cg = blockIdx.x;
  const int tid = threadIdx.x, w = tid >> 6, lane = tid & 63;
  const int fr = lane & 15, qd = lane >> 4;
  const size_t cb = (size_t)cg * 8192;
  const u16* Sbc = Sb16 + (size_t)cg * 16384;

#pragma unroll
  for (int g = 0; g < 4; ++g) {
    const int pn = 4 * w + g;
    gl_lds16(Qg + cb + pn * 512 + lane * 8, &L[(0 + pn * 1024) >> 1]);
    gl_lds16(O1g + cb + pn * 512 + lane * 8, &L[(49152 + pn * 1024) >> 1]);
  }
#pragma unroll
  for (int g = 0; g < 8; ++g) {
    const int pn = 8 * w + g, ig = pn >> 2, kc = pn & 3;
    gl_lds16(Sbc + (size_t)(ig * 16 + fr) * kM + kc * 32 + qd * 8,
             &L[(16384 + pn * 1024) >> 1]);
  }
  __syncthreads();

  // O2 = Q S^T: wave w -> 16 t-rows x 128 i
  f32x4 o2[8] = {};
#pragma unroll
  for (int kc = 0; kc < 4; ++kc) {
    bf16x8 aq = *(const bf16x8*)&L[(0 + (w * 4 + kc) * 1024 + qd * 256 + fr * 16) >> 1];
#pragma unroll
    for (int ig = 0; ig < 8; ++ig) {
      bf16x8 bS = *(const bf16x8*)&L[(16384 + (ig * 4 + kc) * 1024 + qd * 256 + fr * 16) >> 1];
      o2[ig] = mf(aq, bS, o2[ig]);
    }
  }

  float dt[4];
#pragma unroll
  for (int r = 0; r < 4; ++r) dt[r] = exp2f((float)(w * 16 + qd * 4 + r) * kLog2d);
#pragma unroll
  for (int ig = 0; ig < 8; ++ig)
#pragma unroll
    for (int r = 0; r < 4; ++r) {
      const int t = w * 16 + qd * 4 + r, i2 = ig * 16 + fr;
      const float o1v = bf2f(L[(49152 + fo64x128(t, i2)) >> 1]);
      Outg[cb + (fo64x128(t, i2) >> 1)] = f2bf(fmaf(dt[r], o2[ig][r], o1v));
    }
}

// ---------------------------------------------------------------------------
// out_gemm: y[16384 x 1024] = Out[16384 x 128] @ Woh^T + bo.
// Tile 128 rows x 128 cols, K=128 single-shot (no K-loop). Grid (8 dg,
// 128 rg) = 1024 blocks (~4/CU). LDS 64 KiB: A(Out 2 chunks)@0, B(Woh)@32K.
// ---------------------------------------------------------------------------
__global__ __launch_bounds__(256, 2)
void out_gemm(const u16* __restrict__ Outg, const u16* __restrict__ Woh,
              const float* __restrict__ bo, float* __restrict__ y)
{
  __shared__ __align__(16) u16 L[32768];
  const int dg = blockIdx.x, rg = blockIdx.y;
  const int tid = threadIdx.x, w = tid >> 6, lane = tid & 63;
  const int fr = lane & 15, qd = lane >> 4;
  const size_t ab = (size_t)rg * 16384;   // 2 chunks x 8192 u16

#pragma unroll
  for (int g = 0; g < 8; ++g) {
    const int pn = 8 * w + g;             // 0..31
    gl_lds16(Outg + ab + pn * 512 + lane * 8, &L[(0 + pn * 1024) >> 1]);
    const int pg = pn >> 2, kc = pn & 3;
    gl_lds16(Woh + (size_t)(dg * 128 + pg * 16 + fr) * kM + kc * 32 + qd * 8,
             &L[(32768 + pn * 1024) >> 1]);
  }
  __syncthreads();

  f32x4 acc[2][8] = {};
#pragma unroll
  for (int kc = 0; kc < 4; ++kc) {
    bf16x8 aA[2];
#pragma unroll
    for (int mi = 0; mi < 2; ++mi)
      aA[mi] = *(const bf16x8*)&L[(((w * 2 + mi) * 4 + kc) * 1024 + qd * 256 + fr * 16) >> 1];
#pragma unroll
    for (int nj = 0; nj < 8; ++nj) {
      bf16x8 bB = *(const bf16x8*)&L[(32768 + (nj * 4 + kc) * 1024 + qd * 256 + fr * 16) >> 1];
#pragma unroll
      for (int mi = 0; mi < 2; ++mi)
        acc[mi][nj] = mf(aA[mi], bB, acc[mi][nj]);
    }
  }

#pragma unroll
  for (int nj = 0; nj < 8; ++nj) {
    const int d = dg * 128 + nj * 16 + fr;
    const float bb = bo[d];
#pragma unroll
    for (int mi = 0; mi < 2; ++mi)
#pragma unroll
      for (int r = 0; r < 4; ++r) {
        const int row = rg * 128 + w * 32 + mi * 16 + qd * 4 + r;
        y[(size_t)row * kD + d] = acc[mi][nj][r] + bb;
      }
  }
}

// ---------------------------------------------------------------------------
extern "C" void kernel_launch(void* const* d_in, const int* in_sizes, int n_in,
                              void* d_out, int out_size, void* d_ws, size_t ws_size,
                              hipStream_t stream) {
  const float* x  = (const float*)d_in[0];
  const float* Wk = (const float*)d_in[1];
  const float* bk = (const float*)d_in[2];
  const float* Wv = (const float*)d_in[3];
  const float* bv = (const float*)d_in[4];
  const float* Wq = (const float*)d_in[5];
  const float* bq = (const float*)d_in[6];
  const float* Wo = (const float*)d_in[7];
  const float* bo = (const float*)d_in[8];

  char* wsp = (char*)d_ws;
  u16* Wkvq = (u16*)wsp;  wsp += (size_t)384 * 1024 * 2;
  u16* Woh  = (u16*)wsp;  wsp += (size_t)1024 * 128 * 2;
  u16* Qg   = (u16*)wsp;  wsp += (size_t)kNCG * 8192 * 2;          // 4 MB
  u16* Kg   = (u16*)wsp;  wsp += (size_t)kNCG * 8192 * 2;          // 4 MB
  u16* Outg = Kg;                                                   // alias: Kg dead after intra
  u16* VTg  = (u16*)wsp;
  u16* KwTg = VTg + (size_t)kNCG * 8192;
  u16* Sb16 = VTg;                                                  // alias: VTg/KwTg dead after intra
  wsp += (size_t)kNCG * 16384 * 2;                                  // 8 MB
  u16* O1g  = (u16*)wsp;  wsp += (size_t)kNCG * 8192 * 2;          // 4 MB
  float* SU = (float*)wsp; wsp += (size_t)kNCG * 16384 * 4;        // 16 MB

  float* y = (float*)d_out;
  float* state_out = y + (size_t)kRS * kD;

  cast_w_kernel<<<dim3(512), dim3(256), 0, stream>>>(Wk, Wv, Wq, Wo, Wkvq, Woh);
  proj_gemm<<<dim3(kNCG, 3), dim3(256), 0, stream>>>(x, Wkvq, bk, bv, bq, Qg, Kg, VTg, KwTg);
  intra_kernel<<<dim3(kNCG), dim3(256), 0, stream>>>(Qg, Kg, VTg, KwTg, O1g, SU);
  scan_kernel<<<dim3(kB * 16384 / 256), dim3(256), 0, stream>>>(SU, Sb16, state_out);
  combine_kernel<<<dim3(kNCG), dim3(256), 0, stream>>>(Qg, Sb16, O1g, Outg);
  out_gemm<<<dim3(8, 128), dim3(256), 0, stream>>>(Outg, Woh, bo, y);
}